// Round 2
// baseline (2060.196 us; speedup 1.0000x reference)
//
#include <hip/hip_runtime.h>

#define B_ 256
#define T_ 500
#define N_ 256
#define BN_ 65536            // B_*N_
#define STP_ 196608          // 3*B_*N_ (states per-t stride)

// ---------------------------------------------------------------------------
// W1t[k][n] = W1[n][k]  (256x256 fp32)
// ---------------------------------------------------------------------------
__global__ __launch_bounds__(256)
void w1_transpose_kernel(const float* __restrict__ W1, float* __restrict__ W1t) {
    __shared__ float tile[32][33];
    const int bx = blockIdx.x & 7;
    const int by = blockIdx.x >> 3;
    const int tx = threadIdx.x & 31;
    const int ty = threadIdx.x >> 5;  // 0..7
#pragma unroll
    for (int i = 0; i < 4; ++i)
        tile[ty + 8 * i][tx] = W1[(by * 32 + ty + 8 * i) * 256 + bx * 32 + tx];
    __syncthreads();
#pragma unroll
    for (int i = 0; i < 4; ++i)
        W1t[(bx * 32 + ty + 8 * i) * 256 + by * 32 + tx] = tile[tx][ty + 8 * i];
}

// ---------------------------------------------------------------------------
// I = X @ W1^T fp32, X viewed [B*T=128000, 256] (contiguous). Output scattered
// into the v-plane of states: states[t*STP + b*256 + n], b=m/500, t=m%500.
// 128x128 tile, BK=16, 256 threads, 8x8 microtile, double-buffered LDS,
// ONE barrier per K-chunk. A tile k-major [16][132] (pad -> 2-way = free;
// A-frag reads are 16-lane broadcasts). B tile [16][128] from W1t (k-major).
// grid = (1000, 2).
// ---------------------------------------------------------------------------
__global__ __launch_bounds__(256, 4)
void gemm_kernel(const float* __restrict__ X, const float* __restrict__ W1t,
                 float* __restrict__ states) {
    __shared__ float As[2][16 * 132];
    __shared__ float Bs[2][16 * 128];

    const int tid = threadIdx.x;
    const int m0  = blockIdx.x << 7;
    const int n0  = blockIdx.y << 7;

    // A staging: thread covers rows ar, ar+64 at k-quad akq
    const int ar  = tid >> 2;            // 0..63
    const int akq = (tid & 3) << 2;      // 0,4,8,12
    // B staging: rows bkr, bkr+8 at col-quad bnc
    const int bkr = tid >> 5;            // 0..7
    const int bnc = (tid & 31) << 2;     // 0..124

    const float* Xa = X + (size_t)(m0 + ar) * 256 + akq;
    const float* Xb = Xa + (size_t)64 * 256;
    const float* Wb = W1t + (size_t)bkr * 256 + n0 + bnc;

    float4 ra0 = *(const float4*)(Xa);
    float4 ra1 = *(const float4*)(Xb);
    float4 rb0 = *(const float4*)(Wb);
    float4 rb1 = *(const float4*)(Wb + 8 * 256);

    float acc[8][8];
#pragma unroll
    for (int i = 0; i < 8; ++i)
#pragma unroll
        for (int j = 0; j < 8; ++j) acc[i][j] = 0.f;

    const int tm0 = (tid >> 4) << 3;     // 0..120
    const int tn0 = (tid & 15) << 3;     // 0..120

    for (int c = 0; c < 16; ++c) {
        float* Ac = &As[c & 1][0];
        float* Bc = &Bs[c & 1][0];
        // regs -> LDS (A transposed to k-major)
#pragma unroll
        for (int j = 0; j < 4; ++j) {
            Ac[(akq + j) * 132 + ar]      = ((const float*)&ra0)[j];
            Ac[(akq + j) * 132 + ar + 64] = ((const float*)&ra1)[j];
        }
        *(float4*)&Bc[bkr * 128 + bnc]       = rb0;
        *(float4*)&Bc[(bkr + 8) * 128 + bnc] = rb1;
        __syncthreads();   // one barrier/iter: next write to buf (c+1)&1 is
                           // separated from its last readers (iter c-1) by this
        if (c < 15) {      // prefetch next chunk; latency hidden under 16 kks
            const int k0 = (c + 1) << 4;
            ra0 = *(const float4*)(Xa + k0);
            ra1 = *(const float4*)(Xb + k0);
            rb0 = *(const float4*)(Wb + (size_t)k0 * 256);
            rb1 = *(const float4*)(Wb + (size_t)(k0 + 8) * 256);
        }
#pragma unroll
        for (int kk = 0; kk < 16; ++kk) {
            const float4 a0 = *(const float4*)&Ac[kk * 132 + tm0];
            const float4 a1 = *(const float4*)&Ac[kk * 132 + tm0 + 4];
            const float4 b0 = *(const float4*)&Bc[kk * 128 + tn0];
            const float4 b1 = *(const float4*)&Bc[kk * 128 + tn0 + 4];
            const float av[8] = {a0.x, a0.y, a0.z, a0.w, a1.x, a1.y, a1.z, a1.w};
            const float bv[8] = {b0.x, b0.y, b0.z, b0.w, b1.x, b1.y, b1.z, b1.w};
#pragma unroll
            for (int i = 0; i < 8; ++i)
#pragma unroll
                for (int j = 0; j < 8; ++j)
                    acc[i][j] += av[i] * bv[j];
        }
    }

#pragma unroll
    for (int i = 0; i < 8; ++i) {
        const int m = m0 + tm0 + i;
        const int b = m / 500;           // magic-mul
        const int t = m - b * 500;
        float* dst = states + (size_t)t * STP_ + (size_t)b * 256 + n0 + tn0;
        *(float4*)(dst)     = make_float4(acc[i][0], acc[i][1], acc[i][2], acc[i][3]);
        *(float4*)(dst + 4) = make_float4(acc[i][4], acc[i][5], acc[i][6], acc[i][7]);
    }
}

// ---------------------------------------------------------------------------
// Sequential Izhikevich scan. One block per batch b, one thread per neuron n.
// v,u in registers for all 500 steps. I[t] read from the states v-plane
// (written by gemm) and overwritten in place by v_new (same thread).
// li readout: in-wave shuffle reduce (no barrier), wave leaders stash
// partials; ONE barrier per 8 steps flushes 8 dots to LDS dots[500];
// thread 0 runs the li recurrence after the loop.
// ---------------------------------------------------------------------------
__global__ __launch_bounds__(256)
void scan_kernel(float* __restrict__ states, float* __restrict__ out_s,
                 float* __restrict__ out_dec,
                 const float* __restrict__ st_snn, const float* __restrict__ st_li,
                 const float* __restrict__ W2,
                 const float* __restrict__ pa, const float* __restrict__ pb,
                 const float* __restrict__ pc, const float* __restrict__ pd,
                 const float* __restrict__ pv0, const float* __restrict__ pv1,
                 const float* __restrict__ pv2, const float* __restrict__ ptau,
                 const float* __restrict__ pth, const float* __restrict__ pleak) {
    const int bb   = blockIdx.x;
    const int tid  = threadIdx.x;
    const int boff = bb * 256 + tid;
    const int w    = tid >> 6;
    const int lane = tid & 63;

    float v = st_snn[boff];
    float u = st_snn[BN_ + boff];

    const float a_   = pa[tid];
    const float b_   = pb[tid];
    const float c_   = pc[tid];
    const float d_   = pd[tid];
    const float v0_  = pv0[tid];
    const float v1_  = pv1[tid];
    const float v2_  = pv2[tid];
    const float coef = (1.0f / ptau[tid]) * a_;  // (DT/tau_u)*a, DT=1
    const float th_  = pth[tid];
    const float w2_  = W2[tid];

    __shared__ float dots[T_];
    __shared__ float red[2][8][4];

    // prefetch pipeline depth 4 (static indices via unroll-4)
    float Ib[4];
#pragma unroll
    for (int q = 0; q < 4; ++q) Ib[q] = states[(size_t)q * STP_ + boff];

    for (int tb = 0; tb < T_; tb += 4) {
#pragma unroll
        for (int q = 0; q < 4; ++q) {
            const int t = tb + q;
            const size_t pbase = (size_t)t * STP_ + boff;
            const float Icur = Ib[q];
            if (t + 4 < T_) Ib[q] = states[pbase + (size_t)4 * STP_];

            const float vm = v + (((v2_ * v * v + v1_ * v) + v0_ - u) + Icur);
            const float um = u + coef * (b_ * v - u);
            const bool  sp = (vm - th_) > 0.f;
            const float s  = sp ? 1.f : 0.f;
            v = sp ? c_ : vm;            // == vm*(1-s)+s*c exactly, s in {0,1}
            u = sp ? (um + d_) : um;     // == um + s*d

            states[pbase]           = v;  // overwrite consumed I with v_new
            states[pbase + BN_]     = u;
            states[pbase + 2 * BN_] = s;
            out_s[(size_t)t * BN_ + boff] = s;

            float ds = s * w2_;
#pragma unroll
            for (int off = 1; off < 64; off <<= 1) ds += __shfl_xor(ds, off);
            if (lane == 0) red[(t >> 3) & 1][t & 7][w] = ds;
            if ((t & 7) == 7) {          // uniform condition -> legal barrier
                __syncthreads();
                if (tid < 8) {
                    const float* rp = red[(t >> 3) & 1][tid];
                    dots[t - 7 + tid] = (rp[0] + rp[1]) + (rp[2] + rp[3]);
                }
            }
        }
    }
    // tail: t=496..499 (500%8 != 0) never hit the flush above
    __syncthreads();
    if (tid < 4) {
        const float* rp = red[0][tid];   // 496>>3 = 62 -> half 0
        dots[496 + tid] = (rp[0] + rp[1]) + (rp[2] + rp[3]);
    }
    __syncthreads();

    if (tid == 0) {
        const float lk_  = pleak[0];
        const float olk_ = 1.0f - lk_;
        float li = st_li[bb];
        for (int t = 0; t < T_; ++t) {
            li = lk_ * li + olk_ * dots[t];
            out_dec[(size_t)t * 256 + bb] = li;
        }
    }
}

// ---------------------------------------------------------------------------
extern "C" void kernel_launch(void* const* d_in, const int* in_sizes, int n_in,
                              void* d_out, int out_size, void* d_ws, size_t ws_size,
                              hipStream_t stream) {
    const float* input  = (const float*)d_in[0];   // [B,T,N]
    const float* st_snn = (const float*)d_in[1];   // [3,B,N]
    const float* st_li  = (const float*)d_in[2];   // [B,1]
    const float* W1     = (const float*)d_in[3];   // [N,N]
    const float* W2     = (const float*)d_in[4];   // [1,N]
    const float* pa     = (const float*)d_in[5];
    const float* pb     = (const float*)d_in[6];
    const float* pc     = (const float*)d_in[7];
    const float* pd     = (const float*)d_in[8];
    const float* pv0    = (const float*)d_in[9];
    const float* pv1    = (const float*)d_in[10];
    const float* pv2    = (const float*)d_in[11];
    const float* ptau   = (const float*)d_in[12];
    const float* pth    = (const float*)d_in[13];
    const float* pleak  = (const float*)d_in[14];

    float* out        = (float*)d_out;
    float* out_s      = out;                                        // [500,256,256]
    float* out_states = out + (size_t)T_ * BN_;                     // [500,3,256,256]
    float* out_dec    = out + (size_t)T_ * BN_ + (size_t)T_ * STP_; // [500,256]

    // W1^T scratch lives in the decoded region (256KB of 512KB); scan fully
    // overwrites it at the end. No dependence on ws_size.
    float* W1t = out_dec;

    w1_transpose_kernel<<<dim3(64), dim3(256), 0, stream>>>(W1, W1t);
    gemm_kernel<<<dim3(1000, 2), dim3(256), 0, stream>>>(input, W1t, out_states);
    scan_kernel<<<dim3(B_), dim3(256), 0, stream>>>(
        out_states, out_s, out_dec, st_snn, st_li, W2,
        pa, pb, pc, pd, pv0, pv1, pv2, ptau, pth, pleak);
}

// Round 3
// 1328.033 us; speedup vs baseline: 1.5513x; 1.5513x over previous
//
#include <hip/hip_runtime.h>

#define B_ 256
#define T_ 500
#define N_ 256
#define BN_ 65536            // B_*N_
#define STP_ 196608          // 3*B_*N_ (states per-t stride)

// ---------------------------------------------------------------------------
// W1t[k][n] = W1[n][k]  (256x256 fp32)
// ---------------------------------------------------------------------------
__global__ __launch_bounds__(256)
void w1_transpose_kernel(const float* __restrict__ W1, float* __restrict__ W1t) {
    __shared__ float tile[32][33];
    const int bx = blockIdx.x & 7;
    const int by = blockIdx.x >> 3;
    const int tx = threadIdx.x & 31;
    const int ty = threadIdx.x >> 5;  // 0..7
#pragma unroll
    for (int i = 0; i < 4; ++i)
        tile[ty + 8 * i][tx] = W1[(by * 32 + ty + 8 * i) * 256 + bx * 32 + tx];
    __syncthreads();
#pragma unroll
    for (int i = 0; i < 4; ++i)
        W1t[(bx * 32 + ty + 8 * i) * 256 + by * 32 + tx] = tile[tx][ty + 8 * i];
}

// ---------------------------------------------------------------------------
// I = X @ W1^T fp32 with M ordered as (t, b): block = (t0 fixed, 128 b's).
// Output rows (t0, b) are CONTIGUOUS 1-KB rows in the states v-plane ->
// dense 64-KB half-stripes per block (no scatter, ~1x HBM write).
// A-reads: X rows (b, t0) at 512-KB stride, 1 KB each, read once per n-tile.
// 128x128 tile, BK=16, 256 threads, 8x8 microtile, double-buffered LDS,
// one barrier per K-chunk. grid = (1000, 2): x -> (t0 = bx>>1, b-half), y -> n-half.
// ---------------------------------------------------------------------------
__global__ __launch_bounds__(256, 4)
void gemm_kernel(const float* __restrict__ X, const float* __restrict__ W1t,
                 float* __restrict__ states) {
    __shared__ float As[2][16 * 132];   // [k][m], pad 132 -> 2-way (free)
    __shared__ float Bs[2][16 * 128];   // [k][n]

    const int tid = threadIdx.x;
    const int t0  = blockIdx.x >> 1;
    const int b0  = (blockIdx.x & 1) << 7;
    const int n0  = blockIdx.y << 7;

    // A staging: thread covers b-rows (b0+ar, b0+ar+64) at k-quad akq
    const int ar  = tid >> 2;            // 0..63
    const int akq = (tid & 3) << 2;      // 0,4,8,12
    // B staging: k-rows (bkr, bkr+8) at col-quad bnc
    const int bkr = tid >> 5;            // 0..7
    const int bnc = (tid & 31) << 2;     // 0..124

    const float* Xa = X + (size_t)(b0 + ar) * (T_ * 256) + (size_t)t0 * 256 + akq;
    const float* Xb = Xa + (size_t)64 * (T_ * 256);
    const float* Wb = W1t + (size_t)bkr * 256 + n0 + bnc;

    float4 ra0 = *(const float4*)(Xa);
    float4 ra1 = *(const float4*)(Xb);
    float4 rb0 = *(const float4*)(Wb);
    float4 rb1 = *(const float4*)(Wb + 8 * 256);

    float acc[8][8];
#pragma unroll
    for (int i = 0; i < 8; ++i)
#pragma unroll
        for (int j = 0; j < 8; ++j) acc[i][j] = 0.f;

    const int tm0 = (tid >> 4) << 3;     // m-microtile base: 0..120
    const int tn0 = (tid & 15) << 2;     // n cols {tn0..tn0+3, tn0+64..+67} -> dense stores

    for (int c = 0; c < 16; ++c) {
        float* Ac = &As[c & 1][0];
        float* Bc = &Bs[c & 1][0];
#pragma unroll
        for (int j = 0; j < 4; ++j) {    // regs -> LDS (A transposed to k-major)
            Ac[(akq + j) * 132 + ar]      = ((const float*)&ra0)[j];
            Ac[(akq + j) * 132 + ar + 64] = ((const float*)&ra1)[j];
        }
        *(float4*)&Bc[bkr * 128 + bnc]       = rb0;
        *(float4*)&Bc[(bkr + 8) * 128 + bnc] = rb1;
        __syncthreads();                 // one barrier/iter (dbuf makes it safe)
        if (c < 15) {                    // prefetch next chunk under the FMAs
            const int k0 = (c + 1) << 4;
            ra0 = *(const float4*)(Xa + k0);
            ra1 = *(const float4*)(Xb + k0);
            rb0 = *(const float4*)(Wb + (size_t)k0 * 256);
            rb1 = *(const float4*)(Wb + (size_t)(k0 + 8) * 256);
        }
#pragma unroll
        for (int kk = 0; kk < 16; ++kk) {
            const float4 a0 = *(const float4*)&Ac[kk * 132 + tm0];
            const float4 a1 = *(const float4*)&Ac[kk * 132 + tm0 + 4];
            const float4 bl = *(const float4*)&Bc[kk * 128 + tn0];
            const float4 bh = *(const float4*)&Bc[kk * 128 + tn0 + 64];
            const float av[8] = {a0.x, a0.y, a0.z, a0.w, a1.x, a1.y, a1.z, a1.w};
            const float bv[8] = {bl.x, bl.y, bl.z, bl.w, bh.x, bh.y, bh.z, bh.w};
#pragma unroll
            for (int i = 0; i < 8; ++i)
#pragma unroll
                for (int j = 0; j < 8; ++j)
                    acc[i][j] += av[i] * bv[j];
        }
    }

    // epilogue: rows are consecutive b at fixed t0 -> 1-KB-strided dense writes
#pragma unroll
    for (int i = 0; i < 8; ++i) {
        float* dst = states + (size_t)t0 * STP_ + (size_t)(b0 + tm0 + i) * 256 + n0 + tn0;
        *(float4*)(dst)      = make_float4(acc[i][0], acc[i][1], acc[i][2], acc[i][3]);
        *(float4*)(dst + 64) = make_float4(acc[i][4], acc[i][5], acc[i][6], acc[i][7]);
    }
}

// ---------------------------------------------------------------------------
// Sequential Izhikevich scan. One block per batch b, one thread per neuron n.
// v,u in registers for all 500 steps. I[t] read from the states v-plane
// (written by gemm) and overwritten in place by v_new (same thread).
// NO in-loop barriers: wave leaders stash per-wave dot partials in
// dotw[500][4]; one barrier at the end; thread 0 runs the li recurrence.
// I prefetched 16 steps ahead (covers ~900-cy HBM latency).
// ---------------------------------------------------------------------------
__global__ __launch_bounds__(256)
void scan_kernel(float* __restrict__ states, float* __restrict__ out_s,
                 float* __restrict__ out_dec,
                 const float* __restrict__ st_snn, const float* __restrict__ st_li,
                 const float* __restrict__ W2,
                 const float* __restrict__ pa, const float* __restrict__ pb,
                 const float* __restrict__ pc, const float* __restrict__ pd,
                 const float* __restrict__ pv0, const float* __restrict__ pv1,
                 const float* __restrict__ pv2, const float* __restrict__ ptau,
                 const float* __restrict__ pth, const float* __restrict__ pleak) {
    const int bb   = blockIdx.x;
    const int tid  = threadIdx.x;
    const int boff = bb * 256 + tid;
    const int w    = tid >> 6;
    const int lane = tid & 63;

    float v = st_snn[boff];
    float u = st_snn[BN_ + boff];

    const float a_   = pa[tid];
    const float b_   = pb[tid];
    const float c_   = pc[tid];
    const float d_   = pd[tid];
    const float v0_  = pv0[tid];
    const float v1_  = pv1[tid];
    const float v2_  = pv2[tid];
    const float coef = (1.0f / ptau[tid]) * a_;  // (DT/tau_u)*a, DT=1
    const float th_  = pth[tid];
    const float w2_  = W2[tid];

    __shared__ float dotw[T_][4];                // 8 KB of per-wave partials

    float Ib[16];
#pragma unroll
    for (int q = 0; q < 16; ++q) Ib[q] = states[(size_t)q * STP_ + boff];

#define STEP(TT, QQ) do {                                                   \
        const int t = (TT);                                                 \
        const size_t pbase = (size_t)t * STP_ + boff;                       \
        const float Icur = Ib[QQ];                                          \
        if (t + 16 < T_) Ib[QQ] = states[pbase + (size_t)16 * STP_];        \
        const float vm = v + (((v2_ * v * v + v1_ * v) + v0_ - u) + Icur);  \
        const float um = u + coef * (b_ * v - u);                           \
        const bool  sp = (vm - th_) > 0.f;                                  \
        const float s  = sp ? 1.f : 0.f;                                    \
        v = sp ? c_ : vm;                                                   \
        u = sp ? (um + d_) : um;                                            \
        states[pbase]           = v;                                        \
        states[pbase + BN_]     = u;                                        \
        states[pbase + 2 * BN_] = s;                                        \
        out_s[(size_t)t * BN_ + boff] = s;                                  \
        float ds = s * w2_;                                                 \
        ds += __shfl_xor(ds, 1);  ds += __shfl_xor(ds, 2);                  \
        ds += __shfl_xor(ds, 4);  ds += __shfl_xor(ds, 8);                  \
        ds += __shfl_xor(ds, 16); ds += __shfl_xor(ds, 32);                 \
        if (lane == 0) dotw[t][w] = ds;                                     \
    } while (0)

    for (int tb = 0; tb < 496; tb += 16) {
#pragma unroll
        for (int q = 0; q < 16; ++q) STEP(tb + q, q);
    }
#pragma unroll
    for (int q = 0; q < 4; ++q) STEP(496 + q, q);   // t = 496..499
#undef STEP

    __syncthreads();
    if (tid == 0) {
        const float lk_  = pleak[0];
        const float olk_ = 1.0f - lk_;
        float li = st_li[bb];
        for (int t = 0; t < T_; ++t) {
            const float dot = (dotw[t][0] + dotw[t][1]) + (dotw[t][2] + dotw[t][3]);
            li = lk_ * li + olk_ * dot;
            out_dec[(size_t)t * 256 + bb] = li;
        }
    }
}

// ---------------------------------------------------------------------------
extern "C" void kernel_launch(void* const* d_in, const int* in_sizes, int n_in,
                              void* d_out, int out_size, void* d_ws, size_t ws_size,
                              hipStream_t stream) {
    const float* input  = (const float*)d_in[0];   // [B,T,N]
    const float* st_snn = (const float*)d_in[1];   // [3,B,N]
    const float* st_li  = (const float*)d_in[2];   // [B,1]
    const float* W1     = (const float*)d_in[3];   // [N,N]
    const float* W2     = (const float*)d_in[4];   // [1,N]
    const float* pa     = (const float*)d_in[5];
    const float* pb     = (const float*)d_in[6];
    const float* pc     = (const float*)d_in[7];
    const float* pd     = (const float*)d_in[8];
    const float* pv0    = (const float*)d_in[9];
    const float* pv1    = (const float*)d_in[10];
    const float* pv2    = (const float*)d_in[11];
    const float* ptau   = (const float*)d_in[12];
    const float* pth    = (const float*)d_in[13];
    const float* pleak  = (const float*)d_in[14];

    float* out        = (float*)d_out;
    float* out_s      = out;                                        // [500,256,256]
    float* out_states = out + (size_t)T_ * BN_;                     // [500,3,256,256]
    float* out_dec    = out + (size_t)T_ * BN_ + (size_t)T_ * STP_; // [500,256]

    // W1^T scratch lives in the decoded region (256KB of 512KB); scan fully
    // overwrites it at the end. No dependence on ws_size.
    float* W1t = out_dec;

    w1_transpose_kernel<<<dim3(64), dim3(256), 0, stream>>>(W1, W1t);
    gemm_kernel<<<dim3(1000, 2), dim3(256), 0, stream>>>(input, W1t, out_states);
    scan_kernel<<<dim3(B_), dim3(256), 0, stream>>>(
        out_states, out_s, out_dec, st_snn, st_li, W2,
        pa, pb, pc, pd, pv0, pv1, pv2, ptau, pth, pleak);
}

// Round 4
// 486.679 us; speedup vs baseline: 4.2332x; 2.7288x over previous
//
#include <hip/hip_runtime.h>

#define B_ 256
#define T_ 500
#define N_ 256
#define BN_ 65536            // B_*N_
#define STP_ 196608          // 3*B_*N_ (states per-t stride)
#define TW 64                // t-window per chunk
#define NCHUNK 8             // ceil(500/64)

// ---------------------------------------------------------------------------
// Fused GEMM + Izhikevich scan. One block per batch b (256 blocks x 256 thr).
// Per chunk of 64 timesteps:
//   phase A: stage X[b, t0:t0+64, 0:256] into LDS k-major  (Al[k][t], 64 KB)
//   phase G: I = X_chunk @ W1^T entirely on-chip. 4x16 microtile per thread,
//            W1 BK=16 slices staged (transposed) from L2 into double-buffered
//            Ws[2][16][256]; acc[4][16] in registers; k-order identical to
//            the previous separate GEMM (bit-identical spikes).
//   phase I: acc -> Al reinterpreted as I[t][n]  (overwrites consumed A)
//   phase S: 64 scan steps; I from LDS (conflict-free), v/u in registers,
//            mandatory global stores only; per-wave dot partials to dotw[][].
// After all chunks: thread 0 runs the 500-step li recurrence from dotw.
// I never touches HBM. X is read exactly once. W1 re-staged per chunk (L2).
// ---------------------------------------------------------------------------
__global__ __launch_bounds__(256)
void fused_snn_kernel(const float* __restrict__ X, const float* __restrict__ W1,
                      float* __restrict__ out_s, float* __restrict__ states,
                      float* __restrict__ out_dec,
                      const float* __restrict__ st_snn, const float* __restrict__ st_li,
                      const float* __restrict__ W2,
                      const float* __restrict__ pa, const float* __restrict__ pb,
                      const float* __restrict__ pc, const float* __restrict__ pd,
                      const float* __restrict__ pv0, const float* __restrict__ pv1,
                      const float* __restrict__ pv2, const float* __restrict__ ptau,
                      const float* __restrict__ pth, const float* __restrict__ pleak) {
    __shared__ float Al[TW * 256];       // 64 KB: A (k-major) then I[t][n]
    __shared__ float Ws[2][16 * 256];    // 32 KB: W1t BK-slice double buffer
    __shared__ float dotw[T_][4];        // 8 KB: per-wave dot partials

    const int bb   = blockIdx.x;
    const int tid  = threadIdx.x;
    const int w    = tid >> 6;
    const int lane = tid & 63;
    const int boff = bb * 256 + tid;

    // scan per-thread state & params
    float v = st_snn[boff];
    float u = st_snn[BN_ + boff];
    const float a_   = pa[tid];
    const float b_   = pb[tid];
    const float c_   = pc[tid];
    const float d_   = pd[tid];
    const float v0_  = pv0[tid];
    const float v1_  = pv1[tid];
    const float v2_  = pv2[tid];
    const float coef = (1.0f / ptau[tid]) * a_;   // (DT/tau_u)*a, DT=1
    const float th_  = pth[tid];
    const float w2_  = W2[tid];

    // microtile coordinates: 16 t-groups x 16 n-groups
    const int g   = tid >> 4;            // t rows g*4 .. g*4+3
    const int h4  = (tid & 15) << 2;     // n cols h4 + 64c + j  (bank-friendly)

    const float* Xb = X + (size_t)bb * (T_ * 256);
    const int tl = tid & 63;             // A-stage t_loc
    const int wq = (tid >> 6) << 2;      // A-stage k sub-quad

    for (int cc = 0; cc < NCHUNK; ++cc) {
        const int t0    = cc * TW;
        const int valid = min(TW, T_ - t0);

        // ---------------- phase A: X chunk -> Al[k][t] ----------------
        {
            const int tsrc = t0 + ((tl < valid) ? tl : (valid - 1));
            const float* Xrow = Xb + (size_t)tsrc * 256;
#pragma unroll
            for (int r = 0; r < 16; ++r) {
                const int k = r * 16 + wq;
                const float4 xv = *(const float4*)(Xrow + k);
                Al[(k + 0) * 64 + tl] = xv.x;     // lanes consecutive: no conflict
                Al[(k + 1) * 64 + tl] = xv.y;
                Al[(k + 2) * 64 + tl] = xv.z;
                Al[(k + 3) * 64 + tl] = xv.w;
            }
        }
        // stage W slice ks=0 into Ws[0]  (Ws[kk][n] = W1[n][kk])
        {
            const float* Wr = W1 + (size_t)tid * 256;   // W1 row n=tid, k0=0
            const float4 w0 = *(const float4*)(Wr + 0);
            const float4 w1 = *(const float4*)(Wr + 4);
            const float4 w2v = *(const float4*)(Wr + 8);
            const float4 w3 = *(const float4*)(Wr + 12);
            float* Wd = &Ws[0][0];
            Wd[ 0*256+tid]=w0.x; Wd[ 1*256+tid]=w0.y; Wd[ 2*256+tid]=w0.z; Wd[ 3*256+tid]=w0.w;
            Wd[ 4*256+tid]=w1.x; Wd[ 5*256+tid]=w1.y; Wd[ 6*256+tid]=w1.z; Wd[ 7*256+tid]=w1.w;
            Wd[ 8*256+tid]=w2v.x; Wd[ 9*256+tid]=w2v.y; Wd[10*256+tid]=w2v.z; Wd[11*256+tid]=w2v.w;
            Wd[12*256+tid]=w3.x; Wd[13*256+tid]=w3.y; Wd[14*256+tid]=w3.z; Wd[15*256+tid]=w3.w;
        }
        __syncthreads();

        // ---------------- phase G: block GEMM, acc in regs ----------------
        float acc[4][16];
#pragma unroll
        for (int i = 0; i < 4; ++i)
#pragma unroll
            for (int j = 0; j < 16; ++j) acc[i][j] = 0.f;

        for (int ks = 0; ks < 16; ++ks) {
            float4 w0, w1, w2v, w3;
            if (ks < 15) {               // issue next-slice loads early
                const float* Wr = W1 + (size_t)tid * 256 + (ks + 1) * 16;
                w0 = *(const float4*)(Wr + 0);
                w1 = *(const float4*)(Wr + 4);
                w2v = *(const float4*)(Wr + 8);
                w3 = *(const float4*)(Wr + 12);
            }
            const float* Wc = &Ws[ks & 1][0];
            const int kbase = ks * 16;
#pragma unroll
            for (int kk = 0; kk < 16; ++kk) {
                const float4 av = *(const float4*)&Al[(kbase + kk) * 64 + (g << 2)];
                const float* Wk = Wc + kk * 256 + h4;
                const float4 b0 = *(const float4*)(Wk);
                const float4 b1 = *(const float4*)(Wk + 64);
                const float4 b2 = *(const float4*)(Wk + 128);
                const float4 b3 = *(const float4*)(Wk + 192);
                const float avr[4] = {av.x, av.y, av.z, av.w};
                const float bvr[16] = {b0.x, b0.y, b0.z, b0.w, b1.x, b1.y, b1.z, b1.w,
                                       b2.x, b2.y, b2.z, b2.w, b3.x, b3.y, b3.z, b3.w};
#pragma unroll
                for (int i = 0; i < 4; ++i)
#pragma unroll
                    for (int j = 0; j < 16; ++j)
                        acc[i][j] += avr[i] * bvr[j];
            }
            if (ks < 15) {               // LDS writes after FMAs (latency hidden)
                float* Wd = &Ws[(ks + 1) & 1][0];
                Wd[ 0*256+tid]=w0.x; Wd[ 1*256+tid]=w0.y; Wd[ 2*256+tid]=w0.z; Wd[ 3*256+tid]=w0.w;
                Wd[ 4*256+tid]=w1.x; Wd[ 5*256+tid]=w1.y; Wd[ 6*256+tid]=w1.z; Wd[ 7*256+tid]=w1.w;
                Wd[ 8*256+tid]=w2v.x; Wd[ 9*256+tid]=w2v.y; Wd[10*256+tid]=w2v.z; Wd[11*256+tid]=w2v.w;
                Wd[12*256+tid]=w3.x; Wd[13*256+tid]=w3.y; Wd[14*256+tid]=w3.z; Wd[15*256+tid]=w3.w;
            }
            __syncthreads();             // also separates ks=15 Al reads from I-write
        }

        // ---------------- phase I: acc -> Al as I[t][n] ----------------
#pragma unroll
        for (int i = 0; i < 4; ++i) {
            const int t = (g << 2) + i;
#pragma unroll
            for (int c = 0; c < 4; ++c)
                *(float4*)&Al[t * 256 + h4 + 64 * c] =
                    make_float4(acc[i][4*c], acc[i][4*c+1], acc[i][4*c+2], acc[i][4*c+3]);
        }
        __syncthreads();

        // ---------------- phase S: scan valid steps ----------------
        float Inx = Al[tid];             // q=0 prefetch
        for (int q = 0; q < valid; ++q) {
            const float Icur = Inx;
            if (q + 1 < valid) Inx = Al[(q + 1) * 256 + tid];
            const int t = t0 + q;
            const size_t pbase = (size_t)t * STP_ + boff;

            const float vm = v + (((v2_ * v * v + v1_ * v) + v0_ - u) + Icur);
            const float um = u + coef * (b_ * v - u);
            const bool  sp = (vm - th_) > 0.f;
            const float s  = sp ? 1.f : 0.f;
            v = sp ? c_ : vm;            // == vm*(1-s)+s*c exactly, s in {0,1}
            u = sp ? (um + d_) : um;     // == um + s*d

            states[pbase]           = v;
            states[pbase + BN_]     = u;
            states[pbase + 2 * BN_] = s;
            out_s[(size_t)t * BN_ + boff] = s;

            float ds = s * w2_;
            ds += __shfl_xor(ds, 1);  ds += __shfl_xor(ds, 2);
            ds += __shfl_xor(ds, 4);  ds += __shfl_xor(ds, 8);
            ds += __shfl_xor(ds, 16); ds += __shfl_xor(ds, 32);
            if (lane == 0) dotw[t][w] = ds;
        }
        __syncthreads();                 // Al reads done before next A-stage
    }

    // ---------------- li recurrence (thread 0) ----------------
    if (tid == 0) {
        const float lk_  = pleak[0];
        const float olk_ = 1.0f - lk_;
        float li = st_li[bb];
        for (int t = 0; t < T_; ++t) {
            const float dot = (dotw[t][0] + dotw[t][1]) + (dotw[t][2] + dotw[t][3]);
            li = lk_ * li + olk_ * dot;
            out_dec[(size_t)t * 256 + bb] = li;
        }
    }
}

// ---------------------------------------------------------------------------
extern "C" void kernel_launch(void* const* d_in, const int* in_sizes, int n_in,
                              void* d_out, int out_size, void* d_ws, size_t ws_size,
                              hipStream_t stream) {
    const float* input  = (const float*)d_in[0];   // [B,T,N]
    const float* st_snn = (const float*)d_in[1];   // [3,B,N]
    const float* st_li  = (const float*)d_in[2];   // [B,1]
    const float* W1     = (const float*)d_in[3];   // [N,N]
    const float* W2     = (const float*)d_in[4];   // [1,N]
    const float* pa     = (const float*)d_in[5];
    const float* pb     = (const float*)d_in[6];
    const float* pc     = (const float*)d_in[7];
    const float* pd     = (const float*)d_in[8];
    const float* pv0    = (const float*)d_in[9];
    const float* pv1    = (const float*)d_in[10];
    const float* pv2    = (const float*)d_in[11];
    const float* ptau   = (const float*)d_in[12];
    const float* pth    = (const float*)d_in[13];
    const float* pleak  = (const float*)d_in[14];

    float* out        = (float*)d_out;
    float* out_s      = out;                                        // [500,256,256]
    float* out_states = out + (size_t)T_ * BN_;                     // [500,3,256,256]
    float* out_dec    = out + (size_t)T_ * BN_ + (size_t)T_ * STP_; // [500,256]

    fused_snn_kernel<<<dim3(B_), dim3(256), 0, stream>>>(
        input, W1, out_s, out_states, out_dec, st_snn, st_li, W2,
        pa, pb, pc, pd, pv0, pv1, pv2, ptau, pth, pleak);
}